// Round 1
// baseline (91.710 us; speedup 1.0000x reference)
//
#include <hip/hip_runtime.h>
#include <hip/hip_bf16.h>
#include <math.h>

// NVAR reservoir: out = GELU(poly_feats(x) @ W1 + b1) @ W2 + b2
// B=2 S=512 E=64 DELAY=5 -> L=320, F = 1 + 320 + 320*321/2 = 51681, tokens = 1024

#define LTERMS 320
#define NF     51681
#define NF_PAD 52224            // 48 * 1088, multiple of 64
#define KSPLIT 48
#define KCH    1088             // K-range per split = 17 chunks of 64
#define MT     64               // tokens per M-tile
#define XW_STRIDE 69            // 68 rows used; stride 69 -> conflict-free staging

typedef __attribute__((ext_vector_type(8))) short short8;
typedef __attribute__((ext_vector_type(4))) float f32x4;

__device__ __forceinline__ unsigned short f2bf(float x) {
    union { float f; unsigned u; } v; v.f = x;
    unsigned r = v.u + 0x7fffu + ((v.u >> 16) & 1u);   // RNE
    return (unsigned short)(r >> 16);
}

// ---- setup: W1T[e][f] = bf16(W1[f][e]), zero-fill pad ----
__global__ void k_setup_w1t(const float* __restrict__ W1, unsigned short* __restrict__ W1T) {
    int f = blockIdx.x * 256 + threadIdx.x;
    if (f >= NF_PAD) return;
    if (f < NF) {
        for (int e = 0; e < 64; ++e)
            W1T[(size_t)e * NF_PAD + f] = f2bf(W1[(size_t)f * 64 + e]);
    } else {
        for (int e = 0; e < 64; ++e)
            W1T[(size_t)e * NF_PAD + f] = 0;
    }
}

__global__ void k_zero(float* __restrict__ p, int n4) {
    int i = blockIdx.x * 256 + threadIdx.x;
    if (i < n4) ((f32x4*)p)[i] = f32x4{0.f, 0.f, 0.f, 0.f};
}

__device__ __forceinline__ int tri_base(int i) {  // #quad features before row i
    return i * LTERMS - ((i * (i - 1)) >> 1);
}

// ---- main GEMM: acc[token][e] += feat[token][k-range] @ W1[k-range][e] ----
__global__ __launch_bounds__(256) void k_main(const float* __restrict__ x,
                                              const unsigned short* __restrict__ W1T,
                                              float* __restrict__ accws) {
    __shared__ float xw[64 * XW_STRIDE];       // [e][r], r = t+k window row
    __shared__ unsigned short ft[MT * 64];     // [t][fc] bf16, row 128B, XOR-swizzled
    __shared__ unsigned short w1s[64 * 64];    // [e][fc] bf16, row 128B, XOR-swizzled

    const int tid = threadIdx.x;
    const int mt = blockIdx.x;                 // 0..15
    const int ky = blockIdx.y;                 // 0..KSPLIT-1
    const int tokbase = mt * MT;
    const int b = mt >> 3, s0 = (mt & 7) * MT;

    // stage x window transposed: xw[e][r] = x[b][s0-4+r][e], r in [0,68)
    for (int idx = tid; idx < 68 * 64; idx += 256) {
        int e = idx & 63, r = idx >> 6;
        int s = s0 - 4 + r;
        float v = (s >= 0) ? x[((b << 9) + s) * 64 + e] : 0.0f;
        xw[e * XW_STRIDE + r] = v;
    }
    __syncthreads();

    const int kb = ky * KCH;
    const int lane = tid & 63, wid = tid >> 6;
    const int t0 = wid * 16;

    f32x4 acc0 = {0.f,0.f,0.f,0.f}, acc1 = {0.f,0.f,0.f,0.f};
    f32x4 acc2 = {0.f,0.f,0.f,0.f}, acc3 = {0.f,0.f,0.f,0.f};

    const int tt  = tid & 63;     // feature-gen: this thread's token
    const int fg  = tid >> 6;     // feature-gen: f-subgroup (16 features)
    const int e_s = tid >> 2;     // w1s staging row
    const int sl0 = tid & 3;      // w1s staging slot

    const int a_t = t0 + (lane & 15);              // A-frag row (token-local)
    const int a_xor = (a_t & 7) << 4;
    const int e0 = lane & 15;
    const int b_xor = (e0 & 7) << 4;               // same for e0+16k (bit3 unchanged)
    char* ftb = (char*)ft;
    char* w1b = (char*)w1s;

    for (int c = 0; c < KCH / 64; ++c) {
        const int f0 = kb + c * 64;

        // issue W1 staging loads early (latency hidden under feature-gen)
        short8 g0 = *(const short8*)(W1T + (size_t)e_s * NF_PAD + f0 + sl0 * 8);
        short8 g1 = *(const short8*)(W1T + (size_t)e_s * NF_PAD + f0 + (sl0 + 4) * 8);

        // generate 16 features for token tt: f in [f0+fg*16, f0+fg*16+16)
        __attribute__((aligned(16))) unsigned short fv[16];
        {
            int ffs = f0 + fg * 16;
            int i = 0, j = 0, icur = -1;
            bool qi = false;
            float vi = 0.f;
            #pragma unroll
            for (int u = 0; u < 16; ++u) {
                int ff = ffs + u;
                float v;
                if (ff >= NF) {
                    v = 0.f;
                } else if (ff == 0) {
                    v = 1.0f;
                } else if (ff <= LTERMS) {
                    int l = ff - 1;
                    v = xw[(l / 5) * XW_STRIDE + tt + (l % 5)];
                } else {
                    if (!qi) {  // decode (i,j) from triangular index once per run
                        int p = ff - (1 + LTERMS);
                        float disc = (float)(410881 - 8 * p);   // 641^2 - 8p
                        i = (int)((641.0f - sqrtf(disc)) * 0.5f);
                        if (i < 0) i = 0;
                        if (i > 319) i = 319;
                        while (i > 0 && tri_base(i) > p) --i;
                        while (i < 319 && tri_base(i + 1) <= p) ++i;
                        j = i + (p - tri_base(i));
                        qi = true;
                    }
                    if (i != icur) { vi = xw[(i / 5) * XW_STRIDE + tt + (i % 5)]; icur = i; }
                    v = vi * xw[(j / 5) * XW_STRIDE + tt + (j % 5)];
                    ++j;
                    if (j == LTERMS) { ++i; j = i; }
                }
                fv[u] = f2bf(v);
            }
        }
        __syncthreads();   // previous chunk's MAC readers done

        {   // swizzled LDS writes
            int wb = e_s * 128 + (((e_s & 7) << 4));
            *(short8*)(w1b + (e_s * 128 + ((sl0 * 16)       ^ ((e_s & 7) << 4)))) = g0;
            *(short8*)(w1b + (e_s * 128 + (((sl0 + 4) * 16) ^ ((e_s & 7) << 4)))) = g1;
            (void)wb;
            *(short8*)(ftb + (tt * 128 + ((fg * 32)        ^ ((tt & 7) << 4)))) = *(short8*)&fv[0];
            *(short8*)(ftb + (tt * 128 + ((fg * 32 + 16)   ^ ((tt & 7) << 4)))) = *(short8*)&fv[8];
        }
        __syncthreads();

        // MAC: 2 K32 steps, 1 A-frag + 4 B-frags -> 4 MFMA each
        #pragma unroll
        for (int kk = 0; kk < 2; ++kk) {
            int slotB = (kk * 4 + (lane >> 4)) * 16;
            short8 af = *(const short8*)(ftb + (a_t * 128 + (slotB ^ a_xor)));
            short8 bf0 = *(const short8*)(w1b + ((e0)      * 128 + (slotB ^ b_xor)));
            short8 bf1 = *(const short8*)(w1b + ((e0 + 16) * 128 + (slotB ^ b_xor)));
            short8 bf2 = *(const short8*)(w1b + ((e0 + 32) * 128 + (slotB ^ b_xor)));
            short8 bf3 = *(const short8*)(w1b + ((e0 + 48) * 128 + (slotB ^ b_xor)));
            acc0 = __builtin_amdgcn_mfma_f32_16x16x32_bf16(af, bf0, acc0, 0, 0, 0);
            acc1 = __builtin_amdgcn_mfma_f32_16x16x32_bf16(af, bf1, acc1, 0, 0, 0);
            acc2 = __builtin_amdgcn_mfma_f32_16x16x32_bf16(af, bf2, acc2, 0, 0, 0);
            acc3 = __builtin_amdgcn_mfma_f32_16x16x32_bf16(af, bf3, acc3, 0, 0, 0);
        }
    }

    // C/D frag: col = lane&15, row = (lane>>4)*4 + r   (guide §3, m89-verified)
    {
        int col = lane & 15;
        int rowb = t0 + ((lane >> 4) << 2);
        #pragma unroll
        for (int r = 0; r < 4; ++r) {
            int tok = tokbase + rowb + r;
            atomicAdd(&accws[tok * 64 + col +  0], acc0[r]);
            atomicAdd(&accws[tok * 64 + col + 16], acc1[r]);
            atomicAdd(&accws[tok * 64 + col + 32], acc2[r]);
            atomicAdd(&accws[tok * 64 + col + 48], acc3[r]);
        }
    }
}

// ---- epilogue: out = GELU(acc + b1) @ W2 + b2 ----
__global__ void k_epi(const float* __restrict__ accws, const float* __restrict__ b1,
                      const float* __restrict__ W2, const float* __restrict__ b2,
                      float* __restrict__ out) {
    __shared__ float h[4 * 64];
    int tid = threadIdx.x;
    int t = tid >> 6, e = tid & 63;
    int token = blockIdx.x * 4 + t;
    float pre = accws[token * 64 + e] + b1[e];
    float hv = 0.5f * pre * (1.0f + erff(pre * 0.70710678118654752f));  // exact GELU
    h[t * 64 + e] = hv;
    __syncthreads();
    float s = b2[e];
    #pragma unroll 8
    for (int ee = 0; ee < 64; ++ee)
        s += h[t * 64 + ee] * W2[ee * 64 + e];
    out[token * 64 + e] = s;
}

extern "C" void kernel_launch(void* const* d_in, const int* in_sizes, int n_in,
                              void* d_out, int out_size, void* d_ws, size_t ws_size,
                              hipStream_t stream) {
    const float* x  = (const float*)d_in[0];
    const float* W1 = (const float*)d_in[1];
    const float* b1 = (const float*)d_in[2];
    const float* W2 = (const float*)d_in[3];
    const float* b2 = (const float*)d_in[4];
    float* out = (float*)d_out;

    unsigned short* W1T = (unsigned short*)d_ws;                          // 64*NF_PAD bf16 = 6.7 MB
    float* accws = (float*)((char*)d_ws + (size_t)64 * NF_PAD * 2);       // 1024*64 f32 = 256 KB

    k_setup_w1t<<<NF_PAD / 256, 256, 0, stream>>>(W1, W1T);
    k_zero<<<64, 256, 0, stream>>>(accws, (1024 * 64) / 4);
    k_main<<<dim3(16, KSPLIT), 256, 0, stream>>>(x, W1T, accws);
    k_epi<<<256, 256, 0, stream>>>(accws, b1, W2, b2, out);
}

// Round 2
// 87.059 us; speedup vs baseline: 1.0534x; 1.0534x over previous
//
#include <hip/hip_runtime.h>
#include <hip/hip_bf16.h>
#include <math.h>

// NVAR reservoir: out = GELU(poly_feats(x) @ W1 + b1) @ W2 + b2
// B=2 S=512 E=64 DELAY=5 -> L=320, F = 1 + 320 + 320*321/2 = 51681, tokens = 1024

#define LTERMS 320
#define NF     51681
#define GRID_KY 101
#define KCH    512             // features per ky-block = 8 chunks of 64
#define NF_PAD (GRID_KY * KCH) // 51712
#define MT     64              // tokens per M-tile
#define XW_STRIDE 69           // floats; row byte stride 276

typedef __attribute__((ext_vector_type(8))) short short8;
typedef __attribute__((ext_vector_type(4))) float f32x4;

__device__ __forceinline__ unsigned short f2bf(float x) {
    return __bfloat16_as_ushort(__float2bfloat16(x));
}

__device__ __forceinline__ int tri_base(int i) {  // #quad features before row i
    return i * LTERMS - ((i * (i - 1)) >> 1);
}

// ---- setup: W1T[e][f] = bf16(W1[f][e]) (pad zero), + zero acc buffer ----
__global__ void k_setup(const float* __restrict__ W1, unsigned short* __restrict__ W1T,
                        float* __restrict__ accws) {
    int bx = blockIdx.x;
    if (bx >= NF_PAD / 256) {           // tail blocks zero the accumulator
        int i = (bx - NF_PAD / 256) * 1024 + threadIdx.x * 4;
        *(f32x4*)(accws + i) = f32x4{0.f, 0.f, 0.f, 0.f};
        return;
    }
    int f = bx * 256 + threadIdx.x;
    if (f < NF) {
        #pragma unroll
        for (int e4 = 0; e4 < 16; ++e4) {
            f32x4 v = *(const f32x4*)(W1 + (size_t)f * 64 + e4 * 4);
            #pragma unroll
            for (int k = 0; k < 4; ++k)
                W1T[(size_t)(e4 * 4 + k) * NF_PAD + f] = f2bf(v[k]);
        }
    } else {
        #pragma unroll
        for (int e = 0; e < 64; ++e)
            W1T[(size_t)e * NF_PAD + f] = 0;
    }
}

// ---- main GEMM: acc[token][e] += feat[token][k-range] @ W1[k-range][e] ----
__global__ __launch_bounds__(256, 4) void k_main(const float* __restrict__ x,
                                                 const unsigned short* __restrict__ W1T,
                                                 float* __restrict__ accws) {
    __shared__ float xw[68 * XW_STRIDE];       // [e][r], r = t+k window row
    __shared__ unsigned short ft[MT * 64];     // [t][fc] bf16, row 128B, XOR-swizzled
    __shared__ unsigned short w1s[64 * 64];    // [e][fc] bf16, row 128B, XOR-swizzled

    const int tid = threadIdx.x;
    const int mt = blockIdx.x;                 // 0..15
    const int ky = blockIdx.y;                 // 0..GRID_KY-1
    const int tokbase = mt * MT;
    const int b = mt >> 3, s0 = (mt & 7) * MT;

    // stage x window transposed: xw[e][r] = x[b][s0-4+r][e], r in [0,68)
    for (int idx = tid; idx < 68 * 64; idx += 256) {
        int e = idx & 63, r = idx >> 6;
        int s = s0 - 4 + r;
        float v = (s >= 0) ? x[((b << 9) + s) * 64 + e] : 0.0f;
        xw[e * XW_STRIDE + r] = v;
    }
    __syncthreads();

    const int kb = ky * KCH;
    const int lane = tid & 63, wid = tid >> 6;
    const int t0 = wid * 16;

    f32x4 acc0 = {0.f,0.f,0.f,0.f}, acc1 = {0.f,0.f,0.f,0.f};
    f32x4 acc2 = {0.f,0.f,0.f,0.f}, acc3 = {0.f,0.f,0.f,0.f};

    const int tt  = lane;                    // feature-gen: this thread's token
    const int fg  = __builtin_amdgcn_readfirstlane(wid); // wave-uniform f-subgroup
    const int tt4 = tt * 4;
    const int e_s = tid >> 2;                // w1s staging row
    const int sl0 = tid & 3;                 // w1s staging slot

    const int a_t = t0 + (lane & 15);        // A-frag row (token-local)
    const int a_xor = (a_t & 7) << 4;
    const int e0 = lane & 15;
    const int b_xor = (e0 & 7) << 4;
    char* ftb = (char*)ft;
    char* w1b = (char*)w1s;
    const char* xwb = (const char*)xw;

    // wave-uniform quadratic-enumeration state (SGPRs):
    int qi = 0, qj = 0, jm5 = 0, sjo = 0, sio = 0;
    bool inq = false;
    float vi = 0.f;                          // per-lane value of row element i

    for (int c = 0; c < KCH / 64; ++c) {
        const int f0 = kb + c * 64;

        // issue W1 staging loads early (latency hidden under feature-gen)
        short8 g0 = *(const short8*)(W1T + (size_t)e_s * NF_PAD + f0 + sl0 * 8);
        short8 g1 = *(const short8*)(W1T + (size_t)e_s * NF_PAD + f0 + (sl0 + 4) * 8);

        // generate 16 features for token tt: f in [f0+fg*16, +16)
        const int ffs = f0 + fg * 16;
        float fvf[16];
        #pragma unroll
        for (int u = 0; u < 16; ++u) {
            const int ff = ffs + u;          // wave-uniform
            float v;
            if (ff >= NF) {
                v = 0.f;
            } else if (ff == 0) {
                v = 1.0f;
            } else if (ff <= LTERMS) {
                int l = ff - 1;
                v = *(const float*)(xwb + ((l / 5) * 276 + (l % 5) * 4 + tt4));
            } else {
                if (!inq) {                  // one-time decode (binary search, scalar)
                    int p = ff - (1 + LTERMS);
                    int lo = 0, hi = LTERMS;
                    while (hi - lo > 1) { int mid = (lo + hi) >> 1;
                                          if (tri_base(mid) <= p) lo = mid; else hi = mid; }
                    qi = lo; qj = qi + (p - tri_base(qi));
                    sio = (qi / 5) * 276 + (qi % 5) * 4;
                    jm5 = qj % 5; sjo = (qj / 5) * 276 + jm5 * 4;
                    vi = *(const float*)(xwb + (sio + tt4));
                    inq = true;
                }
                float vj = *(const float*)(xwb + (sjo + tt4));
                v = vi * vj;
                // advance one position (all-scalar state updates)
                if (qj == LTERMS - 1) {      // row wrap: (i,319) -> (i+1,i+1)
                    ++qi; qj = qi;
                    int qm = qi % 5;
                    sio = (qi / 5) * 276 + qm * 4;
                    jm5 = qm; sjo = sio;
                    vi = *(const float*)(xwb + (sio + tt4));
                } else {
                    ++qj; ++jm5; sjo += 4;
                    if (jm5 == 5) { jm5 = 0; sjo += 256; }
                }
            }
            fvf[u] = v;
        }
        // bulk-advance 48 positions to next chunk's run start
        if (inq) {
            qj += 48;
            while (qj >= LTERMS && qi < LTERMS - 1) { qj = qi + 1 + (qj - LTERMS); ++qi; }
            if (qj >= LTERMS) qj = LTERMS - 1;   // only pad features follow
            sio = (qi / 5) * 276 + (qi % 5) * 4;
            jm5 = qj % 5; sjo = (qj / 5) * 276 + jm5 * 4;
            vi = *(const float*)(xwb + (sio + tt4));
        }

        // pack to bf16
        __attribute__((aligned(16))) unsigned short fu[16];
        #pragma unroll
        for (int u = 0; u < 16; ++u) fu[u] = f2bf(fvf[u]);

        __syncthreads();   // previous chunk's MAC readers done

        {   // swizzled LDS writes
            *(short8*)(w1b + (e_s * 128 + ((sl0 * 16)       ^ ((e_s & 7) << 4)))) = g0;
            *(short8*)(w1b + (e_s * 128 + (((sl0 + 4) * 16) ^ ((e_s & 7) << 4)))) = g1;
            *(short8*)(ftb + (tt * 128 + ((fg * 32)        ^ ((tt & 7) << 4)))) = *(short8*)&fu[0];
            *(short8*)(ftb + (tt * 128 + ((fg * 32 + 16)   ^ ((tt & 7) << 4)))) = *(short8*)&fu[8];
        }
        __syncthreads();

        // MAC: 2 K32 steps, 1 A-frag + 4 B-frags -> 4 MFMA each
        #pragma unroll
        for (int kk = 0; kk < 2; ++kk) {
            int slotB = (kk * 4 + (lane >> 4)) * 16;
            short8 af  = *(const short8*)(ftb + (a_t * 128 + (slotB ^ a_xor)));
            short8 bf0 = *(const short8*)(w1b + ((e0)      * 128 + (slotB ^ b_xor)));
            short8 bf1 = *(const short8*)(w1b + ((e0 + 16) * 128 + (slotB ^ b_xor)));
            short8 bf2 = *(const short8*)(w1b + ((e0 + 32) * 128 + (slotB ^ b_xor)));
            short8 bf3 = *(const short8*)(w1b + ((e0 + 48) * 128 + (slotB ^ b_xor)));
            acc0 = __builtin_amdgcn_mfma_f32_16x16x32_bf16(af, bf0, acc0, 0, 0, 0);
            acc1 = __builtin_amdgcn_mfma_f32_16x16x32_bf16(af, bf1, acc1, 0, 0, 0);
            acc2 = __builtin_amdgcn_mfma_f32_16x16x32_bf16(af, bf2, acc2, 0, 0, 0);
            acc3 = __builtin_amdgcn_mfma_f32_16x16x32_bf16(af, bf3, acc3, 0, 0, 0);
        }
    }

    // C/D frag: col = lane&15, row = (lane>>4)*4 + r   (guide §3, m89-verified)
    {
        int col = lane & 15;
        int rowb = t0 + ((lane >> 4) << 2);
        #pragma unroll
        for (int r = 0; r < 4; ++r) {
            int tok = tokbase + rowb + r;
            atomicAdd(&accws[tok * 64 + col +  0], acc0[r]);
            atomicAdd(&accws[tok * 64 + col + 16], acc1[r]);
            atomicAdd(&accws[tok * 64 + col + 32], acc2[r]);
            atomicAdd(&accws[tok * 64 + col + 48], acc3[r]);
        }
    }
}

// ---- epilogue: out = GELU(acc + b1) @ W2 + b2 ----
__global__ void k_epi(const float* __restrict__ accws, const float* __restrict__ b1,
                      const float* __restrict__ W2, const float* __restrict__ b2,
                      float* __restrict__ out) {
    __shared__ float h[4 * 64];
    int tid = threadIdx.x;
    int t = tid >> 6, e = tid & 63;
    int token = blockIdx.x * 4 + t;
    float pre = accws[token * 64 + e] + b1[e];
    float hv = 0.5f * pre * (1.0f + erff(pre * 0.70710678118654752f));  // exact GELU
    h[t * 64 + e] = hv;
    __syncthreads();
    float s = b2[e];
    #pragma unroll 8
    for (int ee = 0; ee < 64; ++ee)
        s += h[t * 64 + ee] * W2[ee * 64 + e];
    out[token * 64 + e] = s;
}

extern "C" void kernel_launch(void* const* d_in, const int* in_sizes, int n_in,
                              void* d_out, int out_size, void* d_ws, size_t ws_size,
                              hipStream_t stream) {
    const float* x  = (const float*)d_in[0];
    const float* W1 = (const float*)d_in[1];
    const float* b1 = (const float*)d_in[2];
    const float* W2 = (const float*)d_in[3];
    const float* b2 = (const float*)d_in[4];
    float* out = (float*)d_out;

    unsigned short* W1T = (unsigned short*)d_ws;                          // 64*NF_PAD bf16 ~ 6.6 MB
    float* accws = (float*)((char*)d_ws + (size_t)64 * NF_PAD * 2);       // 1024*64 f32 = 256 KB

    k_setup<<<NF_PAD / 256 + 64, 256, 0, stream>>>(W1, W1T, accws);       // 202 transpose + 64 zero
    k_main<<<dim3(16, GRID_KY), 256, 0, stream>>>(x, W1T, accws);
    k_epi<<<256, 256, 0, stream>>>(accws, b1, W2, b2, out);
}

// Round 3
// 84.819 us; speedup vs baseline: 1.0812x; 1.0264x over previous
//
#include <hip/hip_runtime.h>
#include <hip/hip_bf16.h>
#include <math.h>

// NVAR reservoir: out = GELU(poly_feats(x) @ W1 + b1) @ W2 + b2
// B=2 S=512 E=64 DELAY=5 -> L=320, F = 1 + 320 + 320*321/2 = 51681, tokens = 1024
//
// R3: split-K reduction via per-ky partial buffers + epilogue reduce.
// R2's rocprof showed k_main was bound by 6.6M device-scope atomicAdds
// (WRITE_SIZE == atomics*4B, ~37 atomics/cyc memory-side => ~73us).

#define LTERMS 320
#define NF     51681
#define KY     64              // split-K blocks; grid 16*64=1024 = 4 blocks/CU exactly
#define KCH    832             // features per ky-block = 13 chunks of 64
#define NF_PAD (KY * KCH)      // 53248
#define MT     64              // tokens per M-tile
#define XW_STRIDE 69           // floats; row byte stride 276

typedef __attribute__((ext_vector_type(8))) short short8;
typedef __attribute__((ext_vector_type(4))) float f32x4;

#define W1T_BYTES ((size_t)64 * NF_PAD * 2)            // 6,815,744
#define PART_BYTES ((size_t)KY * 1024 * 64 * 4)        // 16,777,216

__device__ __forceinline__ unsigned short f2bf(float x) {
    return __bfloat16_as_ushort(__float2bfloat16(x));
}

__device__ __forceinline__ int tri_base(int i) {  // #quad features before row i
    return i * LTERMS - ((i * (i - 1)) >> 1);
}

// ---- setup: W1T[e][f] = bf16(W1[f][e]) (pad zero); tail blocks zero 256KB of pbuf
//      (needed only for the atomic fallback; harmless in split mode) ----
__global__ void k_setup(const float* __restrict__ W1, unsigned short* __restrict__ W1T,
                        float* __restrict__ pbuf) {
    int bx = blockIdx.x;
    if (bx >= NF_PAD / 256) {
        int i = (bx - NF_PAD / 256) * 1024 + threadIdx.x * 4;
        *(f32x4*)(pbuf + i) = f32x4{0.f, 0.f, 0.f, 0.f};
        return;
    }
    int f = bx * 256 + threadIdx.x;
    if (f < NF) {
        #pragma unroll
        for (int e4 = 0; e4 < 16; ++e4) {
            f32x4 v = *(const f32x4*)(W1 + (size_t)f * 64 + e4 * 4);
            #pragma unroll
            for (int k = 0; k < 4; ++k)
                W1T[(size_t)(e4 * 4 + k) * NF_PAD + f] = f2bf(v[k]);
        }
    } else {
        #pragma unroll
        for (int e = 0; e < 64; ++e)
            W1T[(size_t)e * NF_PAD + f] = 0;
    }
}

// ---- main GEMM: part[ky][token][e] = feat[token][k-range] @ W1[k-range][e] ----
template<bool SPLIT>
__global__ __launch_bounds__(256, 4) void k_main(const float* __restrict__ x,
                                                 const unsigned short* __restrict__ W1T,
                                                 float* __restrict__ pbuf) {
    __shared__ float xw[68 * XW_STRIDE];       // [e][r], r = t+k window row
    __shared__ unsigned short ft[MT * 64];     // [t][fc] bf16, row 128B, XOR-swizzled
    __shared__ unsigned short w1s[64 * 64];    // [e][fc] bf16, row 128B, XOR-swizzled

    const int tid = threadIdx.x;
    const int mt = blockIdx.x;                 // 0..15
    const int ky = blockIdx.y;                 // 0..KY-1
    const int tokbase = mt * MT;
    const int b = mt >> 3, s0 = (mt & 7) * MT;

    // stage x window transposed: xw[e][r] = x[b][s0-4+r][e], r in [0,68)
    for (int idx = tid; idx < 68 * 64; idx += 256) {
        int e = idx & 63, r = idx >> 6;
        int s = s0 - 4 + r;
        float v = (s >= 0) ? x[((b << 9) + s) * 64 + e] : 0.0f;
        xw[e * XW_STRIDE + r] = v;
    }
    __syncthreads();

    const int kb = ky * KCH;
    const int lane = tid & 63, wid = tid >> 6;
    const int t0 = wid * 16;

    f32x4 acc0 = {0.f,0.f,0.f,0.f}, acc1 = {0.f,0.f,0.f,0.f};
    f32x4 acc2 = {0.f,0.f,0.f,0.f}, acc3 = {0.f,0.f,0.f,0.f};

    const int tt  = lane;                    // feature-gen: this thread's token
    const int fg  = __builtin_amdgcn_readfirstlane(wid); // wave-uniform f-subgroup
    const int tt4 = tt * 4;
    const int e_s = tid >> 2;                // w1s staging row
    const int sl0 = tid & 3;                 // w1s staging slot

    const int a_t = t0 + (lane & 15);        // A-frag row (token-local)
    const int a_xor = (a_t & 7) << 4;
    const int e0 = lane & 15;
    const int b_xor = (e0 & 7) << 4;
    char* ftb = (char*)ft;
    char* w1b = (char*)w1s;
    const char* xwb = (const char*)xw;

    // wave-uniform quadratic-enumeration state (SGPRs):
    int qi = 0, qj = 0, jm5 = 0, sjo = 0, sio = 0;
    bool inq = false;
    float vi = 0.f;                          // per-lane value of row element i

    for (int c = 0; c < KCH / 64; ++c) {
        const int f0 = kb + c * 64;

        // issue W1 staging loads early (latency hidden under feature-gen)
        short8 g0 = *(const short8*)(W1T + (size_t)e_s * NF_PAD + f0 + sl0 * 8);
        short8 g1 = *(const short8*)(W1T + (size_t)e_s * NF_PAD + f0 + (sl0 + 4) * 8);

        // generate 16 features for token tt: f in [f0+fg*16, +16)
        const int ffs = f0 + fg * 16;
        float fvf[16];
        #pragma unroll
        for (int u = 0; u < 16; ++u) {
            const int ff = ffs + u;          // wave-uniform
            float v;
            if (ff >= NF) {
                v = 0.f;
            } else if (ff == 0) {
                v = 1.0f;
            } else if (ff <= LTERMS) {
                int l = ff - 1;
                v = *(const float*)(xwb + ((l / 5) * 276 + (l % 5) * 4 + tt4));
            } else {
                if (!inq) {                  // one-time decode (binary search, scalar)
                    int p = ff - (1 + LTERMS);
                    int lo = 0, hi = LTERMS;
                    while (hi - lo > 1) { int mid = (lo + hi) >> 1;
                                          if (tri_base(mid) <= p) lo = mid; else hi = mid; }
                    qi = lo; qj = qi + (p - tri_base(qi));
                    sio = (qi / 5) * 276 + (qi % 5) * 4;
                    jm5 = qj % 5; sjo = (qj / 5) * 276 + jm5 * 4;
                    vi = *(const float*)(xwb + (sio + tt4));
                    inq = true;
                }
                float vj = *(const float*)(xwb + (sjo + tt4));
                v = vi * vj;
                // advance one position (all-scalar state updates)
                if (qj == LTERMS - 1) {      // row wrap: (i,319) -> (i+1,i+1)
                    ++qi; qj = qi;
                    int qm = qi % 5;
                    sio = (qi / 5) * 276 + qm * 4;
                    jm5 = qm; sjo = sio;
                    vi = *(const float*)(xwb + (sio + tt4));
                } else {
                    ++qj; ++jm5; sjo += 4;
                    if (jm5 == 5) { jm5 = 0; sjo += 256; }
                }
            }
            fvf[u] = v;
        }
        // bulk-advance 48 positions to next chunk's run start
        if (inq) {
            qj += 48;
            while (qj >= LTERMS && qi < LTERMS - 1) { qj = qi + 1 + (qj - LTERMS); ++qi; }
            if (qj >= LTERMS) qj = LTERMS - 1;   // only pad features follow
            sio = (qi / 5) * 276 + (qi % 5) * 4;
            jm5 = qj % 5; sjo = (qj / 5) * 276 + jm5 * 4;
            vi = *(const float*)(xwb + (sio + tt4));
        }

        // pack to bf16
        __attribute__((aligned(16))) unsigned short fu[16];
        #pragma unroll
        for (int u = 0; u < 16; ++u) fu[u] = f2bf(fvf[u]);

        __syncthreads();   // previous chunk's MAC readers done

        {   // swizzled LDS writes
            *(short8*)(w1b + (e_s * 128 + ((sl0 * 16)       ^ ((e_s & 7) << 4)))) = g0;
            *(short8*)(w1b + (e_s * 128 + (((sl0 + 4) * 16) ^ ((e_s & 7) << 4)))) = g1;
            *(short8*)(ftb + (tt * 128 + ((fg * 32)        ^ ((tt & 7) << 4)))) = *(short8*)&fu[0];
            *(short8*)(ftb + (tt * 128 + ((fg * 32 + 16)   ^ ((tt & 7) << 4)))) = *(short8*)&fu[8];
        }
        __syncthreads();

        // MAC: 2 K32 steps, 1 A-frag + 4 B-frags -> 4 MFMA each
        #pragma unroll
        for (int kk = 0; kk < 2; ++kk) {
            int slotB = (kk * 4 + (lane >> 4)) * 16;
            short8 af  = *(const short8*)(ftb + (a_t * 128 + (slotB ^ a_xor)));
            short8 bf0 = *(const short8*)(w1b + ((e0)      * 128 + (slotB ^ b_xor)));
            short8 bf1 = *(const short8*)(w1b + ((e0 + 16) * 128 + (slotB ^ b_xor)));
            short8 bf2 = *(const short8*)(w1b + ((e0 + 32) * 128 + (slotB ^ b_xor)));
            short8 bf3 = *(const short8*)(w1b + ((e0 + 48) * 128 + (slotB ^ b_xor)));
            acc0 = __builtin_amdgcn_mfma_f32_16x16x32_bf16(af, bf0, acc0, 0, 0, 0);
            acc1 = __builtin_amdgcn_mfma_f32_16x16x32_bf16(af, bf1, acc1, 0, 0, 0);
            acc2 = __builtin_amdgcn_mfma_f32_16x16x32_bf16(af, bf2, acc2, 0, 0, 0);
            acc3 = __builtin_amdgcn_mfma_f32_16x16x32_bf16(af, bf3, acc3, 0, 0, 0);
        }
    }

    // C/D frag: col = lane&15, row = (lane>>4)*4 + r   (guide §3, m89-verified)
    {
        int col = lane & 15;
        int rowb = t0 + ((lane >> 4) << 2);
        if (SPLIT) {
            float* dst = pbuf + ((size_t)ky << 16);       // 1024*64 floats per ky
            #pragma unroll
            for (int r = 0; r < 4; ++r) {
                int tok = tokbase + rowb + r;
                dst[tok * 64 + col +  0] = acc0[r];
                dst[tok * 64 + col + 16] = acc1[r];
                dst[tok * 64 + col + 32] = acc2[r];
                dst[tok * 64 + col + 48] = acc3[r];
            }
        } else {
            #pragma unroll
            for (int r = 0; r < 4; ++r) {
                int tok = tokbase + rowb + r;
                atomicAdd(&pbuf[tok * 64 + col +  0], acc0[r]);
                atomicAdd(&pbuf[tok * 64 + col + 16], acc1[r]);
                atomicAdd(&pbuf[tok * 64 + col + 32], acc2[r]);
                atomicAdd(&pbuf[tok * 64 + col + 48], acc3[r]);
            }
        }
    }
}

// ---- epilogue: out = GELU(reduce(part) + b1) @ W2 + b2 ----
template<bool SPLIT>
__global__ void k_epi(const float* __restrict__ pbuf, const float* __restrict__ b1,
                      const float* __restrict__ W2, const float* __restrict__ b2,
                      float* __restrict__ out) {
    __shared__ float h[4 * 64];
    int tid = threadIdx.x;
    int t = tid >> 6, e = tid & 63;
    int token = blockIdx.x * 4 + t;
    float pre;
    if (SPLIT) {
        const float* p = pbuf + token * 64 + e;
        float s0 = 0.f, s1 = 0.f, s2 = 0.f, s3 = 0.f;
        #pragma unroll
        for (int ky = 0; ky < KY; ky += 4) {
            s0 += p[(size_t)(ky + 0) << 16];
            s1 += p[(size_t)(ky + 1) << 16];
            s2 += p[(size_t)(ky + 2) << 16];
            s3 += p[(size_t)(ky + 3) << 16];
        }
        pre = ((s0 + s1) + (s2 + s3)) + b1[e];
    } else {
        pre = pbuf[token * 64 + e] + b1[e];
    }
    float hv = 0.5f * pre * (1.0f + erff(pre * 0.70710678118654752f));  // exact GELU
    h[t * 64 + e] = hv;
    __syncthreads();
    float s = b2[e];
    #pragma unroll 8
    for (int ee = 0; ee < 64; ++ee)
        s += h[t * 64 + ee] * W2[ee * 64 + e];
    out[token * 64 + e] = s;
}

extern "C" void kernel_launch(void* const* d_in, const int* in_sizes, int n_in,
                              void* d_out, int out_size, void* d_ws, size_t ws_size,
                              hipStream_t stream) {
    const float* x  = (const float*)d_in[0];
    const float* W1 = (const float*)d_in[1];
    const float* b1 = (const float*)d_in[2];
    const float* W2 = (const float*)d_in[3];
    const float* b2 = (const float*)d_in[4];
    float* out = (float*)d_out;

    unsigned short* W1T = (unsigned short*)d_ws;
    float* pbuf = (float*)((char*)d_ws + W1T_BYTES);   // partials (split) or acc (fallback)

    const bool split = ws_size >= W1T_BYTES + PART_BYTES;

    k_setup<<<NF_PAD / 256 + 64, 256, 0, stream>>>(W1, W1T, pbuf);
    if (split) {
        k_main<true><<<dim3(16, KY), 256, 0, stream>>>(x, W1T, pbuf);
        k_epi<true><<<256, 256, 0, stream>>>(pbuf, b1, W2, b2, out);
    } else {
        k_main<false><<<dim3(16, KY), 256, 0, stream>>>(x, W1T, pbuf);
        k_epi<false><<<256, 256, 0, stream>>>(pbuf, b1, W2, b2, out);
    }
}

// Round 4
// 80.292 us; speedup vs baseline: 1.1422x; 1.0564x over previous
//
#include <hip/hip_runtime.h>
#include <hip/hip_bf16.h>
#include <math.h>

// NVAR reservoir: out = GELU(poly_feats(x) @ W1 + b1) @ W2 + b2
// B=2 S=512 E=64 DELAY=5 -> L=320, F = 1 + 320 + 320*321/2 = 51681, tokens = 1024
//
// R4: W1T tiled 8KB/chunk (contiguous), B-frags global->registers (no w1s LDS),
// batched A-side ds_reads (offsets precomputed scalar, reads issued together),
// single barrier per chunk with double-buffered ft.

#define LTERMS 320
#define NF     51681
#define KY     64
#define KCH    832
#define NCHUNK (KCH / 64)          // 13
#define NTILE  (KY * NCHUNK)       // 832 tiles of 64 features (cc = ky*13+c)
#define NF_PAD (NTILE * 64)        // 53248
#define MT     64
#define XW_STRIDE 69               // floats; row byte stride 276
#define XW_FLOATS (64 * XW_STRIDE + 276)   // 4692 (layout [64][69] + slack)
#define ONES_OFF  (XW_FLOATS * 4)          // byte offset of ones[64]
#define ZEROS_OFF (ONES_OFF + 256)         // byte offset of zeros[64]
#define XW_TOTAL  (XW_FLOATS + 128)        // 4820 floats

typedef __attribute__((ext_vector_type(8))) short short8;
typedef __attribute__((ext_vector_type(4))) float f32x4;

#define W1T_BYTES ((size_t)NTILE * 8192)        // 6,815,744
#define PART_BYTES ((size_t)KY * 1024 * 64 * 4) // 16,777,216

__device__ __forceinline__ unsigned short f2bf(float x) {
    return __bfloat16_as_ushort(__float2bfloat16(x));
}

__device__ __forceinline__ int tri_base(int i) {  // #quad features before row i
    return i * LTERMS - ((i * (i - 1)) >> 1);
}

__device__ __forceinline__ void quad_init(int pq, int& qi, int& qj, int& jm5,
                                          int& sio, int& sjo) {
    int lo = 0, hi = LTERMS;
    while (hi - lo > 1) { int mid = (lo + hi) >> 1;
                          if (tri_base(mid) <= pq) lo = mid; else hi = mid; }
    qi = lo; qj = qi + (pq - tri_base(qi));
    sio = (qi / 5) * 276 + (qi % 5) * 4;
    jm5 = qj % 5; sjo = (qj / 5) * 276 + jm5 * 4;
}

// ---- setup: W1Tt[cc][e][fi] = bf16(W1[cc*64+fi][e]); tail zeroes pbuf (fallback) ----
__global__ void k_setup(const float* __restrict__ W1, unsigned short* __restrict__ W1T,
                        float* __restrict__ pbuf) {
    int bx = blockIdx.x;
    if (bx >= NTILE) {                       // 64 tail blocks zero 256KB of pbuf
        int i = (bx - NTILE) * 1024 + threadIdx.x * 4;
        *(f32x4*)(pbuf + i) = f32x4{0.f, 0.f, 0.f, 0.f};
        return;
    }
    __shared__ float t[64 * 65];
    const int tid = threadIdx.x;
    const int basef = bx * 64;
    #pragma unroll
    for (int r = 0; r < 16; ++r) {           // coalesced read of 16KB tile
        int idx = r * 256 + tid;             // fi = idx>>6, e = idx&63
        int fi = idx >> 6, e = idx & 63;
        float v = (basef + fi < NF) ? W1[(size_t)(basef + fi) * 64 + e] : 0.f;
        t[fi * 65 + e] = v;
    }
    __syncthreads();
    #pragma unroll
    for (int r = 0; r < 16; ++r) {           // coalesced transposed write
        int idx = r * 256 + tid;             // e = idx>>6, fi = idx&63
        int e = idx >> 6, fi = idx & 63;
        W1T[(size_t)bx * 4096 + idx] = f2bf(t[fi * 65 + e]);
    }
}

// ---- main GEMM: part[ky][token][e] = feat[token][k-range] @ W1[k-range][e] ----
template<bool SPLIT>
__global__ __launch_bounds__(256, 4) void k_main(const float* __restrict__ x,
                                                 const unsigned short* __restrict__ W1T,
                                                 float* __restrict__ pbuf) {
    __shared__ float xw[XW_TOTAL];             // [e<64][r<69] + ones[64] + zeros[64]
    __shared__ unsigned short ftbuf[2][MT * 64];  // double-buffered A tile, swizzled

    const int tid = threadIdx.x;
    const int mt = blockIdx.x;                 // 0..15
    const int ky = blockIdx.y;                 // 0..63
    const int tokbase = mt * MT;
    const int b = mt >> 3, s0 = (mt & 7) * MT;

    for (int idx = tid; idx < 68 * 64; idx += 256) {
        int e = idx & 63, r = idx >> 6;
        int s = s0 - 4 + r;
        xw[e * XW_STRIDE + r] = (s >= 0) ? x[((b << 9) + s) * 64 + e] : 0.f;
    }
    if (tid < 64) { xw[XW_FLOATS + tid] = 1.0f; xw[XW_FLOATS + 64 + tid] = 0.f; }
    __syncthreads();

    const int lane = tid & 63, wid = tid >> 6;
    const int fg = __builtin_amdgcn_readfirstlane(wid);  // wave-uniform f-subgroup
    const int t0 = wid * 16;
    const int tt4 = lane * 4;

    const int a_t = t0 + (lane & 15);          // A-frag row (token-local)
    const int a_xor = (a_t & 7) << 4;
    const int e0 = lane & 15;
    const int ksub = lane >> 4;                // 0..3
    const char* xwb = (const char*)xw;

    f32x4 acc0 = {0.f,0.f,0.f,0.f}, acc1 = {0.f,0.f,0.f,0.f};
    f32x4 acc2 = {0.f,0.f,0.f,0.f}, acc3 = {0.f,0.f,0.f,0.f};

    // wave-uniform quadratic-enumeration state
    int qi = 0, qj = 0, jm5 = 0, sio = 0, sjo = 0;
    bool inq = false;

    const int kb = ky * KCH;
    int p = 0;

    for (int c = 0; c < NCHUNK; ++c) {
        const int f0 = kb + c * 64;
        const unsigned short* tile = W1T + (size_t)(ky * NCHUNK + c) * 4096;

        // ---- B-frags: 8 x 16B direct from the contiguous 8KB tile ----
        short8 bfr[2][4];
        #pragma unroll
        for (int kk = 0; kk < 2; ++kk)
            #pragma unroll
            for (int g = 0; g < 4; ++g)
                bfr[kk][g] = *(const short8*)(tile + (e0 + 16 * g) * 64 + kk * 32 + ksub * 8);

        // ---- scalar phase: compute 16 feature offsets ----
        const int ffs = f0 + fg * 16;
        int offj[16], offi[16];
        int offi0 = ONES_OFF;
        bool fast;

        if (ffs + 15 <= LTERMS) {
            fast = true;                       // all const/linear
            #pragma unroll
            for (int u = 0; u < 16; ++u) {
                int ff = ffs + u;
                offj[u] = (ff == 0) ? ONES_OFF
                                    : (((ff - 1) / 5) * 276 + ((ff - 1) % 5) * 4);
            }
        } else if (ffs > LTERMS) {             // all quad/pad
            if (!inq && ffs < NF) { quad_init(ffs - (1 + LTERMS), qi, qj, jm5, sio, sjo); inq = true; }
            if (inq && (ffs + 15 < NF) && (qj + 15 < LTERMS)) {
                fast = true; offi0 = sio;      // no row wrap in batch
                int o = sjo, m = jm5;
                #pragma unroll
                for (int u = 0; u < 16; ++u) {
                    offj[u] = o;
                    int w = (m == 4);
                    o += w ? 260 : 4;
                    m = w ? 0 : (m + 1);
                }
                qj += 16;                      // sio/sjo/jm5 rebuilt by bulk-advance
            } else {
                fast = false;                  // wraps / pad inside batch
                #pragma unroll
                for (int u = 0; u < 16; ++u) {
                    int ff = ffs + u;
                    if (ff >= NF) { offi[u] = ONES_OFF; offj[u] = ZEROS_OFF; }
                    else {
                        if (!inq) { quad_init(ff - (1 + LTERMS), qi, qj, jm5, sio, sjo); inq = true; }
                        offi[u] = sio; offj[u] = sjo;
                        if (qj == LTERMS - 1) {            // row wrap
                            ++qi; qj = qi;
                            int qm = qi % 5;
                            sio = (qi / 5) * 276 + qm * 4;
                            jm5 = qm; sjo = sio;
                        } else {
                            ++qj; ++jm5; sjo += 4;
                            if (jm5 == 5) { jm5 = 0; sjo += 256; }
                        }
                    }
                }
            }
        } else {                               // mixed linear/quad boundary
            fast = false;
            #pragma unroll
            for (int u = 0; u < 16; ++u) {
                int ff = ffs + u;
                if (ff == 0) { offi[u] = ONES_OFF; offj[u] = ONES_OFF; }
                else if (ff <= LTERMS) {
                    int l = ff - 1;
                    offi[u] = ONES_OFF; offj[u] = (l / 5) * 276 + (l % 5) * 4;
                } else {
                    if (!inq) { quad_init(ff - (1 + LTERMS), qi, qj, jm5, sio, sjo); inq = true; }
                    offi[u] = sio; offj[u] = sjo;
                    if (qj == LTERMS - 1) {
                        ++qi; qj = qi;
                        int qm = qi % 5;
                        sio = (qi / 5) * 276 + qm * 4;
                        jm5 = qm; sjo = sio;
                    } else {
                        ++qj; ++jm5; sjo += 4;
                        if (jm5 == 5) { jm5 = 0; sjo += 256; }
                    }
                }
            }
        }

        if (inq) {   // bulk-advance +48 to this wave's next-chunk run start
            qj += 48;
            while (qj >= LTERMS && qi < LTERMS - 1) { qj = qi + 1 + (qj - LTERMS); ++qi; }
            if (qj >= LTERMS) qj = LTERMS - 1;
            sio = (qi / 5) * 276 + (qi % 5) * 4;
            jm5 = qj % 5; sjo = (qj / 5) * 276 + jm5 * 4;
        }

        // ---- vector phase: batched LDS reads, products, bf16 pack ----
        __attribute__((aligned(16))) unsigned short fu[16];
        if (fast) {
            float vi = *(const float*)(xwb + offi0 + tt4);
            float pj[16];
            #pragma unroll
            for (int u = 0; u < 16; ++u) pj[u] = *(const float*)(xwb + offj[u] + tt4);
            #pragma unroll
            for (int u = 0; u < 16; ++u) fu[u] = f2bf(vi * pj[u]);
        } else {
            float pi[16], pj[16];
            #pragma unroll
            for (int u = 0; u < 16; ++u) pj[u] = *(const float*)(xwb + offj[u] + tt4);
            #pragma unroll
            for (int u = 0; u < 16; ++u) pi[u] = *(const float*)(xwb + offi[u] + tt4);
            #pragma unroll
            for (int u = 0; u < 16; ++u) fu[u] = f2bf(pi[u] * pj[u]);
        }

        // ---- write ft (swizzled), one barrier, MFMA ----
        char* ftb = (char*)ftbuf[p];
        *(short8*)(ftb + (lane * 128 + ((fg * 32)      ^ ((lane & 7) << 4)))) = *(short8*)&fu[0];
        *(short8*)(ftb + (lane * 128 + ((fg * 32 + 16) ^ ((lane & 7) << 4)))) = *(short8*)&fu[8];
        __syncthreads();

        #pragma unroll
        for (int kk = 0; kk < 2; ++kk) {
            int slotB = (kk * 4 + ksub) * 16;
            short8 af = *(const short8*)(ftb + (a_t * 128 + (slotB ^ a_xor)));
            acc0 = __builtin_amdgcn_mfma_f32_16x16x32_bf16(af, bfr[kk][0], acc0, 0, 0, 0);
            acc1 = __builtin_amdgcn_mfma_f32_16x16x32_bf16(af, bfr[kk][1], acc1, 0, 0, 0);
            acc2 = __builtin_amdgcn_mfma_f32_16x16x32_bf16(af, bfr[kk][2], acc2, 0, 0, 0);
            acc3 = __builtin_amdgcn_mfma_f32_16x16x32_bf16(af, bfr[kk][3], acc3, 0, 0, 0);
        }
        p ^= 1;
    }

    // C/D frag: col = lane&15, row = (lane>>4)*4 + r   (guide §3, m89-verified)
    {
        int col = lane & 15;
        int rowb = t0 + ((lane >> 4) << 2);
        if (SPLIT) {
            float* dst = pbuf + ((size_t)ky << 16);       // 1024*64 floats per ky
            #pragma unroll
            for (int r = 0; r < 4; ++r) {
                int tok = tokbase + rowb + r;
                dst[tok * 64 + col +  0] = acc0[r];
                dst[tok * 64 + col + 16] = acc1[r];
                dst[tok * 64 + col + 32] = acc2[r];
                dst[tok * 64 + col + 48] = acc3[r];
            }
        } else {
            #pragma unroll
            for (int r = 0; r < 4; ++r) {
                int tok = tokbase + rowb + r;
                atomicAdd(&pbuf[tok * 64 + col +  0], acc0[r]);
                atomicAdd(&pbuf[tok * 64 + col + 16], acc1[r]);
                atomicAdd(&pbuf[tok * 64 + col + 32], acc2[r]);
                atomicAdd(&pbuf[tok * 64 + col + 48], acc3[r]);
            }
        }
    }
}

// ---- epilogue: out = GELU(reduce(part) + b1) @ W2 + b2 ----
template<bool SPLIT>
__global__ void k_epi(const float* __restrict__ pbuf, const float* __restrict__ b1,
                      const float* __restrict__ W2, const float* __restrict__ b2,
                      float* __restrict__ out) {
    __shared__ float h[4 * 64];
    int tid = threadIdx.x;
    int t = tid >> 6, e = tid & 63;
    int token = blockIdx.x * 4 + t;
    float pre;
    if (SPLIT) {
        const float* p = pbuf + token * 64 + e;
        float s0 = 0.f, s1 = 0.f, s2 = 0.f, s3 = 0.f;
        #pragma unroll
        for (int ky = 0; ky < KY; ky += 4) {
            s0 += p[(size_t)(ky + 0) << 16];
            s1 += p[(size_t)(ky + 1) << 16];
            s2 += p[(size_t)(ky + 2) << 16];
            s3 += p[(size_t)(ky + 3) << 16];
        }
        pre = ((s0 + s1) + (s2 + s3)) + b1[e];
    } else {
        pre = pbuf[token * 64 + e] + b1[e];
    }
    float hv = 0.5f * pre * (1.0f + erff(pre * 0.70710678118654752f));  // exact GELU
    h[t * 64 + e] = hv;
    __syncthreads();
    float s = b2[e];
    #pragma unroll 8
    for (int ee = 0; ee < 64; ++ee)
        s += h[t * 64 + ee] * W2[ee * 64 + e];
    out[token * 64 + e] = s;
}

extern "C" void kernel_launch(void* const* d_in, const int* in_sizes, int n_in,
                              void* d_out, int out_size, void* d_ws, size_t ws_size,
                              hipStream_t stream) {
    const float* x  = (const float*)d_in[0];
    const float* W1 = (const float*)d_in[1];
    const float* b1 = (const float*)d_in[2];
    const float* W2 = (const float*)d_in[3];
    const float* b2 = (const float*)d_in[4];
    float* out = (float*)d_out;

    unsigned short* W1T = (unsigned short*)d_ws;
    float* pbuf = (float*)((char*)d_ws + W1T_BYTES);

    const bool split = ws_size >= W1T_BYTES + PART_BYTES;

    k_setup<<<NTILE + 64, 256, 0, stream>>>(W1, W1T, pbuf);
    if (split) {
        k_main<true><<<dim3(16, KY), 256, 0, stream>>>(x, W1T, pbuf);
        k_epi<true><<<256, 256, 0, stream>>>(pbuf, b1, W2, b2, out);
    } else {
        k_main<false><<<dim3(16, KY), 256, 0, stream>>>(x, W1T, pbuf);
        k_epi<false><<<256, 256, 0, stream>>>(pbuf, b1, W2, b2, out);
    }
}

// Round 6
// 71.988 us; speedup vs baseline: 1.2740x; 1.1153x over previous
//
#include <hip/hip_runtime.h>
#include <hip/hip_bf16.h>
#include <math.h>

// NVAR reservoir: out = GELU(poly_feats(x) @ W1 + b1) @ W2 + b2
// B=2 S=512 E=64 DELAY=5 -> L=320, F=51681, tokens=1024
//
// R6: bilinear reformulation (as R5) with the A-tile swizzle overflow fixed:
// row stride 704 -> 768 B (multiple of 128 so the bit4-6 XOR swizzle is
// bijective in-row; rows bank-aligned). h_pre[t][e] = d'^T M'_e d',
// d' = [320 taps, 1] padded to K=352, N=336. k_main = barrier-free GEMM,
// B fragment-ordered (1KB fully-coalesced frag loads), fused contraction.

#define NF     51681
#define KPAD   352
#define KCHK   11              // 352/32
#define NFR    21              // 336/16
#define NPAD   (NFR * 16)      // 336
#define MT2    128
#define ATS    768             // A-tile row stride in BYTES (multiple of 128!)

typedef __attribute__((ext_vector_type(8))) short short8;
typedef __attribute__((ext_vector_type(4))) float f32x4;

#define W1C_SHORTS ((size_t)64 * NF)                    // 3,307,584
#define MF_SHORTS  ((size_t)64 * KPAD * NPAD)           // 7,569,408
#define W1C_BYTES  (W1C_SHORTS * 2)                     // 6,615,168
#define MF_BYTES   (MF_SHORTS * 2)                      // 15,138,816
#define HBUF_OFF   (W1C_BYTES + MF_BYTES)               // 21,753,984

__device__ __forceinline__ unsigned short f2bf(float x) {
    return __bfloat16_as_ushort(__float2bfloat16(x));
}
__device__ __forceinline__ float bf2f(unsigned short h) {
    union { unsigned u; float f; } v; v.u = ((unsigned)h) << 16; return v.f;
}

// ---- k_t: W1c[e][f] = bf16(W1[f][e]) ----
__global__ void k_t(const float* __restrict__ W1, unsigned short* __restrict__ W1c) {
    __shared__ float t[64 * 65];
    const int tid = threadIdx.x;
    const int f0 = blockIdx.x * 64;
    #pragma unroll
    for (int r = 0; r < 16; ++r) {
        int idx = r * 256 + tid;
        int fi = idx >> 6, e = idx & 63;
        t[fi * 65 + e] = (f0 + fi < NF) ? W1[(size_t)(f0 + fi) * 64 + e] : 0.f;
    }
    __syncthreads();
    #pragma unroll
    for (int r = 0; r < 16; ++r) {
        int idx = r * 256 + tid;
        int e = idx >> 6, fi = idx & 63;
        if (f0 + fi < NF)
            W1c[(size_t)e * NF + f0 + fi] = f2bf(t[fi * 65 + e]);
    }
}

// ---- k_pack: Mfrag in MFMA-fragment order ----
// short index = (((e*11 + kc)*21 + nf)*64 + lane)*8 + r
// j = kc*32 + (lane>>4)*8 + r (K index), i = nf*16 + (lane&15) (N index)
__global__ void k_pack(const unsigned short* __restrict__ W1c,
                       unsigned short* __restrict__ Mfrag) {
    const int g = blockIdx.x * 256 + threadIdx.x;       // < 946176 exactly
    const int lane = g & 63;
    const int rec = g >> 6;                             // < 14784
    const int nf = rec % NFR;
    const int rec2 = rec / NFR;                         // e*11 + kc
    const int kc = rec2 % KCHK;
    const int e = rec2 / KCHK;
    const int i = nf * 16 + (lane & 15);
    const int jb = kc * 32 + ((lane >> 4) << 3);
    const unsigned short* wrow = W1c + (size_t)e * NF;

    __attribute__((aligned(16))) unsigned short v[8];
    #pragma unroll
    for (int r = 0; r < 8; ++r) {
        int j = jb + r;
        unsigned short out = 0;
        if (i < 321 && j < 321) {
            if (j == 320) {
                out = (i == 320) ? wrow[0] : wrow[1 + i];
            } else if (i == 320) {
                out = 0;
            } else {
                int p = min(i, j), q = max(i, j);
                int idx = 321 + p * 320 - ((p * (p - 1)) >> 1) + (q - p);
                unsigned short w = wrow[idx];
                out = (i == j) ? w : f2bf(0.5f * bf2f(w));
            }
        }
        v[r] = out;
    }
    *(short8*)(Mfrag + (size_t)g * 8) = *(short8*)v;
}

// ---- k_main: per block (e, token-tile of 128): C = D' M'_e, h = rowdot(C, D') ----
__global__ __launch_bounds__(512, 1) void k_main(const float* __restrict__ x,
                                                 const unsigned short* __restrict__ Mfrag,
                                                 float* __restrict__ hbuf) {
    __shared__ unsigned short At[MT2 * (ATS / 2)];  // swizzled bf16, row ATS bytes
    __shared__ float xwin[132 * 64];
    __shared__ float hpart[2][4][64];

    const int tid = threadIdx.x;
    const int e = blockIdx.x;                   // e fastest -> 8 token-tiles of an e share an XCD
    const int bx = blockIdx.y;                  // 0..7
    const int tok0 = bx * MT2;
    const int b = bx >> 2, s0 = (bx & 3) * MT2;

    // stage x window: rows r in [0,132), s = s0-4+r
    for (int idx = tid; idx < 132 * 64; idx += 512) {
        int r = idx >> 6, ee = idx & 63;
        int s = s0 - 4 + r;
        xwin[idx] = (s >= 0) ? x[((b << 9) + s) * 64 + ee] : 0.f;
    }
    __syncthreads();

    // build A-tile: At[t][j] = bf16(d'[tok0+t][j]), 8-j records, swizzled
    char* Atb = (char*)At;
    for (int rec = tid; rec < MT2 * 44; rec += 512) {   // 44 = 352/8
        int t = rec / 44, jr = rec - t * 44;
        int j0 = jr * 8;
        __attribute__((aligned(16))) unsigned short hv[8];
        #pragma unroll
        for (int r = 0; r < 8; ++r) {
            int j = j0 + r;
            float v;
            if (j < 320) { int e5 = j / 5, k = j - e5 * 5; v = xwin[(t + k) * 64 + e5]; }
            else v = (j == 320) ? 1.0f : 0.f;
            hv[r] = f2bf(v);
        }
        *(short8*)(Atb + t * ATS + ((j0 * 2) ^ ((t & 7) << 4))) = *(short8*)hv;
    }
    __syncthreads();

    const int lane = tid & 63, wv = tid >> 6;
    const int wm = wv >> 2, wn = wv & 3;        // M-half, N-slice
    const int nf0 = (wn == 0) ? 0 : 6 + (wn - 1) * 5;
    const int nfc = (wn == 0) ? 6 : 5;
    const unsigned short* Bbase = Mfrag + (size_t)e * (KPAD * NPAD);

    f32x4 acc[4][6];
    #pragma unroll
    for (int mf = 0; mf < 4; ++mf)
        #pragma unroll
        for (int q = 0; q < 6; ++q) acc[mf][q] = f32x4{0.f, 0.f, 0.f, 0.f};

    short8 Bc[6], Bn[6], Bn2[6];
    #pragma unroll
    for (int q = 0; q < 6; ++q)
        if (q < nfc) {
            Bc[q] = *(const short8*)(Bbase + ((size_t)((0 * NFR + nf0 + q) * 64 + lane)) * 8);
            Bn[q] = *(const short8*)(Bbase + ((size_t)((1 * NFR + nf0 + q) * 64 + lane)) * 8);
        }

    const int arow = wm * 64 + (lane & 15);     // + mf*16
    const int aslot = (lane >> 4) << 4;         // byte sub-offset within 64B k-chunk

    #pragma unroll 1
    for (int kc = 0; kc < KCHK; ++kc) {
        short8 Af[4];
        #pragma unroll
        for (int mf = 0; mf < 4; ++mf) {
            int t = arow + mf * 16;
            int jb = kc * 64 + aslot;
            Af[mf] = *(const short8*)(Atb + t * ATS + (jb ^ ((t & 7) << 4)));
        }
        if (kc + 2 < KCHK) {
            #pragma unroll
            for (int q = 0; q < 6; ++q)
                if (q < nfc)
                    Bn2[q] = *(const short8*)(Bbase + ((size_t)(((kc + 2) * NFR + nf0 + q) * 64 + lane)) * 8);
        }
        #pragma unroll
        for (int mf = 0; mf < 4; ++mf)
            #pragma unroll
            for (int q = 0; q < 6; ++q)
                if (q < nfc)
                    acc[mf][q] = __builtin_amdgcn_mfma_f32_16x16x32_bf16(Af[mf], Bc[q], acc[mf][q], 0, 0, 0);
        #pragma unroll
        for (int q = 0; q < 6; ++q) { Bc[q] = Bn[q]; Bn[q] = Bn2[q]; }
    }

    // contraction: s[mf][reg] = sum_i C[t][i] * D'[t][i] over this wave's i-slice
    float s[4][4];
    #pragma unroll
    for (int mf = 0; mf < 4; ++mf)
        #pragma unroll
        for (int r = 0; r < 4; ++r) s[mf][r] = 0.f;

    #pragma unroll
    for (int q = 0; q < 6; ++q) {
        if (q < nfc) {
            int i2 = ((nf0 + q) * 16 + (lane & 15)) * 2;
            #pragma unroll
            for (int mf = 0; mf < 4; ++mf)
                #pragma unroll
                for (int r = 0; r < 4; ++r) {
                    int t = wm * 64 + mf * 16 + ((lane >> 4) << 2) + r;
                    unsigned short dv = *(const unsigned short*)(Atb + t * ATS + (i2 ^ ((t & 7) << 4)));
                    s[mf][r] += acc[mf][q][r] * bf2f(dv);
                }
        }
    }
    // reduce across the 16 lanes of each i-column group (masks 1,2,4,8 stay in-group)
    #pragma unroll
    for (int mf = 0; mf < 4; ++mf)
        #pragma unroll
        for (int r = 0; r < 4; ++r) {
            float v = s[mf][r];
            v += __shfl_xor(v, 1);
            v += __shfl_xor(v, 2);
            v += __shfl_xor(v, 4);
            v += __shfl_xor(v, 8);
            s[mf][r] = v;
        }
    if ((lane & 15) == 0) {
        #pragma unroll
        for (int mf = 0; mf < 4; ++mf)
            #pragma unroll
            for (int r = 0; r < 4; ++r)
                hpart[wm][wn][mf * 16 + ((lane >> 4) << 2) + r] = s[mf][r];
    }
    __syncthreads();
    if (tid < 128) {
        int wmx = tid >> 6, tl = tid & 63;
        float v = hpart[wmx][0][tl] + hpart[wmx][1][tl] + hpart[wmx][2][tl] + hpart[wmx][3][tl];
        hbuf[(size_t)(tok0 + wmx * 64 + tl) * 64 + e] = v;
    }
}

// ---- epilogue: out = GELU(hbuf + b1) @ W2 + b2 ----
__global__ void k_epi(const float* __restrict__ hbuf, const float* __restrict__ b1,
                      const float* __restrict__ W2, const float* __restrict__ b2,
                      float* __restrict__ out) {
    __shared__ float h[4 * 64];
    int tid = threadIdx.x;
    int t = tid >> 6, e = tid & 63;
    int token = blockIdx.x * 4 + t;
    float pre = hbuf[token * 64 + e] + b1[e];
    float hv = 0.5f * pre * (1.0f + erff(pre * 0.70710678118654752f));  // exact GELU
    h[t * 64 + e] = hv;
    __syncthreads();
    float s = b2[e];
    #pragma unroll 8
    for (int ee = 0; ee < 64; ++ee)
        s += h[t * 64 + ee] * W2[ee * 64 + e];
    out[token * 64 + e] = s;
}

extern "C" void kernel_launch(void* const* d_in, const int* in_sizes, int n_in,
                              void* d_out, int out_size, void* d_ws, size_t ws_size,
                              hipStream_t stream) {
    const float* x  = (const float*)d_in[0];
    const float* W1 = (const float*)d_in[1];
    const float* b1 = (const float*)d_in[2];
    const float* W2 = (const float*)d_in[3];
    const float* b2 = (const float*)d_in[4];
    float* out = (float*)d_out;

    unsigned short* W1c   = (unsigned short*)d_ws;
    unsigned short* Mfrag = (unsigned short*)((char*)d_ws + W1C_BYTES);
    float* hbuf           = (float*)((char*)d_ws + HBUF_OFF);

    k_t<<<(NF + 63) / 64, 256, 0, stream>>>(W1, W1c);
    k_pack<<<3696, 256, 0, stream>>>(W1c, Mfrag);          // 946176 threads exactly
    k_main<<<dim3(64, 8), 512, 0, stream>>>(x, Mfrag, hbuf);
    k_epi<<<256, 256, 0, stream>>>(hbuf, b1, W2, b2, out);
}

// Round 7
// 68.542 us; speedup vs baseline: 1.3380x; 1.0503x over previous
//
#include <hip/hip_runtime.h>
#include <hip/hip_bf16.h>
#include <math.h>

// NVAR reservoir: out = GELU(poly_feats(x) @ W1 + b1) @ W2 + b2
// B=2 S=512 E=64 DELAY=5 -> L=320, F=51681, tokens=1024
//
// R7: same bilinear formulation as R6 (verified), but k_main now runs
// 1024 threads / 16 waves (wm2 x wn8, mf4) in the same 1-block/CU LDS
// footprint -> 4 waves/SIMD (was 2). Ping-pong B prefetch, hand-unrolled
// kc loop, VGPR ~110 so launch_bounds(1024,4) holds without spill.

#define NF     51681
#define KPAD   352
#define KCHK   11              // 352/32
#define NFR    21              // 336/16
#define NPAD   (NFR * 16)      // 336
#define MT2    128
#define ATS    768             // A-tile row stride in BYTES (multiple of 128)

typedef __attribute__((ext_vector_type(8))) short short8;
typedef __attribute__((ext_vector_type(4))) float f32x4;

#define W1C_SHORTS ((size_t)64 * NF)                    // 3,307,584
#define MF_SHORTS  ((size_t)64 * KPAD * NPAD)           // 7,569,408
#define W1C_BYTES  (W1C_SHORTS * 2)                     // 6,615,168
#define MF_BYTES   (MF_SHORTS * 2)                      // 15,138,816
#define HBUF_OFF   (W1C_BYTES + MF_BYTES)               // 21,753,984

__device__ __forceinline__ unsigned short f2bf(float x) {
    return __bfloat16_as_ushort(__float2bfloat16(x));
}
__device__ __forceinline__ float bf2f(unsigned short h) {
    union { unsigned u; float f; } v; v.u = ((unsigned)h) << 16; return v.f;
}

// ---- k_t: W1c[e][f] = bf16(W1[f][e]) ----
__global__ void k_t(const float* __restrict__ W1, unsigned short* __restrict__ W1c) {
    __shared__ float t[64 * 65];
    const int tid = threadIdx.x;
    const int f0 = blockIdx.x * 64;
    #pragma unroll
    for (int r = 0; r < 16; ++r) {
        int idx = r * 256 + tid;
        int fi = idx >> 6, e = idx & 63;
        t[fi * 65 + e] = (f0 + fi < NF) ? W1[(size_t)(f0 + fi) * 64 + e] : 0.f;
    }
    __syncthreads();
    #pragma unroll
    for (int r = 0; r < 16; ++r) {
        int idx = r * 256 + tid;
        int e = idx >> 6, fi = idx & 63;
        if (f0 + fi < NF)
            W1c[(size_t)e * NF + f0 + fi] = f2bf(t[fi * 65 + e]);
    }
}

// ---- k_pack: Mfrag in MFMA-fragment order ----
// short index = (((e*11 + kc)*21 + nf)*64 + lane)*8 + r
// j = kc*32 + (lane>>4)*8 + r (K index), i = nf*16 + (lane&15) (N index)
__global__ void k_pack(const unsigned short* __restrict__ W1c,
                       unsigned short* __restrict__ Mfrag) {
    const int g = blockIdx.x * 256 + threadIdx.x;       // < 946176 exactly
    const int lane = g & 63;
    const int rec = g >> 6;                             // < 14784
    const int nf = rec % NFR;
    const int rec2 = rec / NFR;                         // e*11 + kc
    const int kc = rec2 % KCHK;
    const int e = rec2 / KCHK;
    const int i = nf * 16 + (lane & 15);
    const int jb = kc * 32 + ((lane >> 4) << 3);
    const unsigned short* wrow = W1c + (size_t)e * NF;

    __attribute__((aligned(16))) unsigned short v[8];
    #pragma unroll
    for (int r = 0; r < 8; ++r) {
        int j = jb + r;
        unsigned short out = 0;
        if (i < 321 && j < 321) {
            if (j == 320) {
                out = (i == 320) ? wrow[0] : wrow[1 + i];
            } else if (i == 320) {
                out = 0;
            } else {
                int p = min(i, j), q = max(i, j);
                int idx = 321 + p * 320 - ((p * (p - 1)) >> 1) + (q - p);
                unsigned short w = wrow[idx];
                out = (i == j) ? w : f2bf(0.5f * bf2f(w));
            }
        }
        v[r] = out;
    }
    *(short8*)(Mfrag + (size_t)g * 8) = *(short8*)v;
}

// ---- k_main: per block (e, token-tile of 128): C = D' M'_e, h = rowdot(C, D') ----
__global__ __launch_bounds__(1024, 4) void k_main(const float* __restrict__ x,
                                                  const unsigned short* __restrict__ Mfrag,
                                                  float* __restrict__ hbuf) {
    __shared__ unsigned short At[MT2 * (ATS / 2)];  // swizzled bf16, row ATS bytes
    __shared__ float xwin[132 * 64];
    __shared__ float hpart[2][8][64];

    const int tid = threadIdx.x;
    const int e = blockIdx.x;                   // e fastest: all 8 tiles of an e -> same XCD
    const int bx = blockIdx.y;                  // 0..7
    const int tok0 = bx * MT2;
    const int b = bx >> 2, s0 = (bx & 3) * MT2;

    // stage x window: rows r in [0,132), s = s0-4+r
    for (int idx = tid; idx < 132 * 64; idx += 1024) {
        int r = idx >> 6, ee = idx & 63;
        int s = s0 - 4 + r;
        xwin[idx] = (s >= 0) ? x[((b << 9) + s) * 64 + ee] : 0.f;
    }
    __syncthreads();

    // build A-tile: At[t][j] = bf16(d'[tok0+t][j]), 8-j records, swizzled
    char* Atb = (char*)At;
    for (int rec = tid; rec < MT2 * 44; rec += 1024) {   // 44 = 352/8
        int t = rec / 44, jr = rec - t * 44;
        int j0 = jr * 8;
        __attribute__((aligned(16))) unsigned short hv[8];
        #pragma unroll
        for (int r = 0; r < 8; ++r) {
            int j = j0 + r;
            float v;
            if (j < 320) { int e5 = j / 5, k = j - e5 * 5; v = xwin[(t + k) * 64 + e5]; }
            else v = (j == 320) ? 1.0f : 0.f;
            hv[r] = f2bf(v);
        }
        *(short8*)(Atb + t * ATS + ((j0 * 2) ^ ((t & 7) << 4))) = *(short8*)hv;
    }
    __syncthreads();

    const int lane = tid & 63, wv = tid >> 6;   // 16 waves
    const int wm = wv >> 3, wn = wv & 7;        // M-half (64 rows), N-slice (of 8)
    const int nfc = (wn < 5) ? 3 : 2;
    const int nf0 = (wn < 5) ? wn * 3 : 15 + (wn - 5) * 2;
    const unsigned short* Bbase = Mfrag + (size_t)e * (KPAD * NPAD);

    f32x4 acc[4][3];
    #pragma unroll
    for (int mf = 0; mf < 4; ++mf)
        #pragma unroll
        for (int q = 0; q < 3; ++q) acc[mf][q] = f32x4{0.f, 0.f, 0.f, 0.f};

    const int arow = wm * 64 + (lane & 15);     // + mf*16
    const int aslot = (lane >> 4) << 4;         // byte sub-offset within 64B k-chunk

    short8 B0[3], B1[3];

#define BLD(DST, KCV)                                                              \
    do { if ((KCV) < KCHK) {                                                       \
        _Pragma("unroll")                                                          \
        for (int q = 0; q < 3; ++q)                                                \
            if (q < nfc)                                                           \
                DST[q] = *(const short8*)(Bbase +                                  \
                    ((size_t)(((KCV) * NFR + nf0 + q) * 64 + lane)) * 8);          \
    } } while (0)

#define STEP(KCV, CUR, NXT)                                                        \
    do {                                                                           \
        short8 Af[4];                                                              \
        _Pragma("unroll")                                                          \
        for (int mf = 0; mf < 4; ++mf) {                                           \
            int t = arow + mf * 16;                                                \
            int jb = (KCV) * 64 + aslot;                                           \
            Af[mf] = *(const short8*)(Atb + t * ATS + (jb ^ ((t & 7) << 4)));      \
        }                                                                          \
        BLD(NXT, (KCV) + 1);                                                       \
        _Pragma("unroll")                                                          \
        for (int mf = 0; mf < 4; ++mf) {                                           \
            _Pragma("unroll")                                                      \
            for (int q = 0; q < 3; ++q)                                            \
                if (q < nfc)                                                       \
                    acc[mf][q] = __builtin_amdgcn_mfma_f32_16x16x32_bf16(          \
                        Af[mf], CUR[q], acc[mf][q], 0, 0, 0);                      \
        }                                                                          \
    } while (0)

    BLD(B0, 0);
    STEP(0, B0, B1);
    STEP(1, B1, B0);
    STEP(2, B0, B1);
    STEP(3, B1, B0);
    STEP(4, B0, B1);
    STEP(5, B1, B0);
    STEP(6, B0, B1);
    STEP(7, B1, B0);
    STEP(8, B0, B1);
    STEP(9, B1, B0);
    STEP(10, B0, B1);
#undef STEP
#undef BLD

    // contraction: s[mf][r] = sum_i C[t][i] * D'[t][i] over this wave's i-slice
    float s[4][4];
    #pragma unroll
    for (int mf = 0; mf < 4; ++mf)
        #pragma unroll
        for (int r = 0; r < 4; ++r) s[mf][r] = 0.f;

    #pragma unroll
    for (int q = 0; q < 3; ++q) {
        if (q < nfc) {
            int i2 = ((nf0 + q) * 16 + (lane & 15)) * 2;
            #pragma unroll
            for (int mf = 0; mf < 4; ++mf)
                #pragma unroll
                for (int r = 0; r < 4; ++r) {
                    int t = wm * 64 + mf * 16 + ((lane >> 4) << 2) + r;
                    unsigned short dv = *(const unsigned short*)(Atb + t * ATS + (i2 ^ ((t & 7) << 4)));
                    s[mf][r] += acc[mf][q][r] * bf2f(dv);
                }
        }
    }
    // reduce across the 16 lanes of each i-column group (masks 1,2,4,8 stay in-group)
    #pragma unroll
    for (int mf = 0; mf < 4; ++mf)
        #pragma unroll
        for (int r = 0; r < 4; ++r) {
            float v = s[mf][r];
            v += __shfl_xor(v, 1);
            v += __shfl_xor(v, 2);
            v += __shfl_xor(v, 4);
            v += __shfl_xor(v, 8);
            s[mf][r] = v;
        }
    if ((lane & 15) == 0) {
        #pragma unroll
        for (int mf = 0; mf < 4; ++mf)
            #pragma unroll
            for (int r = 0; r < 4; ++r)
                hpart[wm][wn][mf * 16 + ((lane >> 4) << 2) + r] = s[mf][r];
    }
    __syncthreads();
    if (tid < 128) {
        int wmx = tid >> 6, tl = tid & 63;
        float v = 0.f;
        #pragma unroll
        for (int w = 0; w < 8; ++w) v += hpart[wmx][w][tl];
        hbuf[(size_t)(tok0 + wmx * 64 + tl) * 64 + e] = v;
    }
}

// ---- epilogue: out = GELU(hbuf + b1) @ W2 + b2 ----
__global__ void k_epi(const float* __restrict__ hbuf, const float* __restrict__ b1,
                      const float* __restrict__ W2, const float* __restrict__ b2,
                      float* __restrict__ out) {
    __shared__ float h[4 * 64];
    int tid = threadIdx.x;
    int t = tid >> 6, e = tid & 63;
    int token = blockIdx.x * 4 + t;
    float pre = hbuf[token * 64 + e] + b1[e];
    float hv = 0.5f * pre * (1.0f + erff(pre * 0.70710678118654752f));  // exact GELU
    h[t * 64 + e] = hv;
    __syncthreads();
    float s = b2[e];
    #pragma unroll 8
    for (int ee = 0; ee < 64; ++ee)
        s += h[t * 64 + ee] * W2[ee * 64 + e];
    out[token * 64 + e] = s;
}

extern "C" void kernel_launch(void* const* d_in, const int* in_sizes, int n_in,
                              void* d_out, int out_size, void* d_ws, size_t ws_size,
                              hipStream_t stream) {
    const float* x  = (const float*)d_in[0];
    const float* W1 = (const float*)d_in[1];
    const float* b1 = (const float*)d_in[2];
    const float* W2 = (const float*)d_in[3];
    const float* b2 = (const float*)d_in[4];
    float* out = (float*)d_out;

    unsigned short* W1c   = (unsigned short*)d_ws;
    unsigned short* Mfrag = (unsigned short*)((char*)d_ws + W1C_BYTES);
    float* hbuf           = (float*)((char*)d_ws + HBUF_OFF);

    k_t<<<(NF + 63) / 64, 256, 0, stream>>>(W1, W1c);
    k_pack<<<3696, 256, 0, stream>>>(W1c, Mfrag);          // 946176 threads exactly
    k_main<<<dim3(64, 8), 1024, 0, stream>>>(x, Mfrag, hbuf);
    k_epi<<<256, 256, 0, stream>>>(hbuf, b1, W2, b2, out);
}